// Round 10
// baseline (242.770 us; speedup 1.0000x reference)
//
#include <hip/hip_runtime.h>
#include <math.h>
#include <stdint.h>

#define S_N 2048
#define X_N 2048
#define G_N 2
#define F_N 3072

#define TM 256
#define TN 128
#define BK 64
#define ITERS (F_N / BK)  // 48
#define NBUF 3

typedef __bf16 bf16;
typedef __bf16 bf16x4 __attribute__((ext_vector_type(4)));
typedef __bf16 bf16x8 __attribute__((ext_vector_type(8)));
typedef float f32x4 __attribute__((ext_vector_type(4)));
typedef int i32x4 __attribute__((ext_vector_type(4)));

__device__ __forceinline__ void gload_lds16(const bf16* g, void* l) {
  __builtin_amdgcn_global_load_lds(
      (const __attribute__((address_space(1))) void*)g,
      (__attribute__((address_space(3))) void*)l, 16, 0, 0);
}

// Software grid barrier: counters zeroed by hipMemsetAsync each launch.
// Release: __threadfence (device scope, flushes per-XCD L2) + agent-scope
// atomicAdd. Acquire: agent-scope atomic load spin (invalidates caches).
// Safe: grid=256 blocks x 144KiB LDS = 1 block/CU on 256 CUs -> co-resident.
__device__ __forceinline__ void gridbar(unsigned int* cnt) {
  __syncthreads();
  if (threadIdx.x == 0) {
    __threadfence();
    __hip_atomic_fetch_add(cnt, 1u, __ATOMIC_ACQ_REL, __HIP_MEMORY_SCOPE_AGENT);
    while (__hip_atomic_load(cnt, __ATOMIC_ACQUIRE, __HIP_MEMORY_SCOPE_AGENT) < 256u) {
      __builtin_amdgcn_s_sleep(8);
    }
  }
  __syncthreads();
}

// Single kernel: prep | gridbar | gemm (R8 core verbatim, flat mapping,
// no XCD swizzle — R9 showed swizzle costs ~3us when L3-fit) | gridbar | lse.
// Targets the measured ~65-70us of inter-dispatch dead time (sum of dispatch
// durs ~87us vs wall 155us, invariant across R0-R9).
__global__ __launch_bounds__(512, 2) void k_mega(
    const float* __restrict__ samples, const float* __restrict__ xin,
    const float* __restrict__ stdv,
    bf16* __restrict__ U, bf16* __restrict__ V,
    float* __restrict__ A, float* __restrict__ C,
    float* __restrict__ logits, float* __restrict__ out,
    unsigned int* __restrict__ sync) {
  __shared__ i32x4 lds[NBUF * 2048 + NBUF * 1024];  // 144 KiB
  int t = threadIdx.x;
  int bid = blockIdx.x;

  // ============ phase 0: prep (R6 body; constg folded into A') ==============
  {
    float* rlds = (float*)lds;  // [0,6144): rinv g0|g1; [6400,6416): partials
    int lane = t & 63, wv = t >> 6;
    for (int i = t; i < 2 * F_N; i += 512) rlds[i] = 1.0f / stdv[i];

    float sl0 = 0.f, sl1 = 0.f;
    for (int i = t; i < F_N; i += 512) {
      sl0 += logf(stdv[i]);
      sl1 += logf(stdv[F_N + i]);
    }
    for (int o = 32; o; o >>= 1) { sl0 += __shfl_xor(sl0, o); sl1 += __shfl_xor(sl1, o); }
    if (lane == 0) { rlds[6400 + wv] = sl0; rlds[6408 + wv] = sl1; }
    __syncthreads();
    float t0 = 0.f, t1 = 0.f;
#pragma unroll
    for (int w2 = 0; w2 < 8; ++w2) { t0 += rlds[6400 + w2]; t1 += rlds[6408 + w2]; }
    const float KLOG = -0.5f * (float)F_N * 1.8378770664093453f;
    float c0 = KLOG - t0, c1 = KLOG - t1;

    int l32 = t & 31;
    int rr = bid * 16 + (t >> 5);      // 0..4095
    bool isS = rr < S_N;
    int rx = isS ? rr : rr - S_N;
    const float* src = isS ? samples + (size_t)rx * F_N : xin + (size_t)rx * F_N;
    bf16* d0 = isS ? U + (size_t)rx * F_N : V + (size_t)rx * F_N;
    bf16* d1 = isS ? U + ((size_t)S_N + rx) * F_N : V + ((size_t)X_N + rx) * F_N;
    float a0 = 0.f, a1 = 0.f;
#pragma unroll 4
    for (int k = 0; k < 24; ++k) {
      int c4 = l32 + k * 32;
      float4 sv = ((const float4*)src)[c4];
      float4 q0 = ((const float4*)rlds)[c4];
      float4 q1 = ((const float4*)rlds)[768 + c4];
      bf16x4 b0, b1;
      b0[0] = (bf16)(sv.x * q0.x); b0[1] = (bf16)(sv.y * q0.y);
      b0[2] = (bf16)(sv.z * q0.z); b0[3] = (bf16)(sv.w * q0.w);
      b1[0] = (bf16)(sv.x * q1.x); b1[1] = (bf16)(sv.y * q1.y);
      b1[2] = (bf16)(sv.z * q1.z); b1[3] = (bf16)(sv.w * q1.w);
      float f0 = (float)b0[0], f1 = (float)b0[1], f2 = (float)b0[2], f3 = (float)b0[3];
      a0 += f0 * f0 + f1 * f1 + f2 * f2 + f3 * f3;
      float h0 = (float)b1[0], h1 = (float)b1[1], h2 = (float)b1[2], h3 = (float)b1[3];
      a1 += h0 * h0 + h1 * h1 + h2 * h2 + h3 * h3;
      ((bf16x4*)d0)[c4] = b0;
      ((bf16x4*)d1)[c4] = b1;
    }
    for (int o = 16; o; o >>= 1) { a0 += __shfl_xor(a0, o); a1 += __shfl_xor(a1, o); }
    if (l32 == 0) {
      if (isS) { A[rx] = a0 - 2.f * c0; A[S_N + rx] = a1 - 2.f * c1; }
      else     { C[rx] = a0;            C[X_N + rx] = a1; }
    }
  }
  gridbar(sync + 0);

  // ============ phase 1: GEMM (R8 core, flat bid mapping) ===================
  {
    i32x4* ldsA = lds;
    i32x4* ldsB = lds + NBUF * 2048;

    int bx = bid & 15, by = (bid >> 4) & 7, g = bid >> 7;
    int bm = by * TM, bn = bx * TN;

    const bf16* Ub = U + ((size_t)g * S_N + bm) * F_N;
    const bf16* Vb = V + ((size_t)g * X_N + bn) * F_N;

    int wave = t >> 6, lane = t & 63;
    int pos = wave >> 1;
    int kh = wave & 1;
    int wm = pos >> 1;
    int wn = pos & 1;
    int r = lane & 15, q = lane >> 4;
    int fr = (r >> 1) & 7;
    int ck = (kh * 4 + q) ^ fr;
    int abase = (wm * 128 + r) * 8;
    int bbase = (wn * 64 + r) * 8;

    int row0 = t >> 3;
    int gcc = (t & 7) ^ ((t >> 4) & 7);
    const bf16* gA[4];
    const bf16* gB[2];
#pragma unroll
    for (int j = 0; j < 4; ++j) gA[j] = Ub + (size_t)(row0 + j * 64) * F_N + gcc * 8;
#pragma unroll
    for (int j = 0; j < 2; ++j) gB[j] = Vb + (size_t)(row0 + j * 64) * F_N + gcc * 8;

    f32x4 acc[8][4] = {};
    bf16x8 af[8], bfr[4];

#pragma unroll
    for (int j = 0; j < 4; ++j) gload_lds16(gA[j], &ldsA[0 * 2048 + t + j * 512]);
#pragma unroll
    for (int j = 0; j < 2; ++j) gload_lds16(gB[j], &ldsB[0 * 1024 + t + j * 512]);
#pragma unroll
    for (int j = 0; j < 4; ++j) gload_lds16(gA[j] + BK, &ldsA[1 * 2048 + t + j * 512]);
#pragma unroll
    for (int j = 0; j < 2; ++j) gload_lds16(gB[j] + BK, &ldsB[1 * 1024 + t + j * 512]);
    asm volatile("s_waitcnt vmcnt(6)" ::: "memory");
    __builtin_amdgcn_s_barrier();
    __builtin_amdgcn_sched_barrier(0);
#pragma unroll
    for (int ni = 0; ni < 4; ++ni)
      bfr[ni] = __builtin_bit_cast(bf16x8, ldsB[bbase + ni * 128 + ck]);
#pragma unroll
    for (int mi = 0; mi < 8; ++mi)
      af[mi] = __builtin_bit_cast(bf16x8, ldsA[abase + mi * 128 + ck]);

    int cur = 0;
    for (int it = 0; it < ITERS; ++it) {
      int k2 = it + 2;
      int pk = (k2 < ITERS ? k2 : 0) * BK;
      int stg = (cur >= 1) ? cur - 1 : 2;
      int nxt = (cur == 2) ? 0 : cur + 1;
      const i32x4* LAn = ldsA + nxt * 2048;
      const i32x4* LBn = ldsB + nxt * 1024;

      gload_lds16(gA[0] + pk, &ldsA[stg * 2048 + t]);
      gload_lds16(gA[1] + pk, &ldsA[stg * 2048 + t + 512]);
      gload_lds16(gA[2] + pk, &ldsA[stg * 2048 + t + 1024]);
      gload_lds16(gA[3] + pk, &ldsA[stg * 2048 + t + 1536]);
      gload_lds16(gB[0] + pk, &ldsB[stg * 1024 + t]);
      gload_lds16(gB[1] + pk, &ldsB[stg * 1024 + t + 512]);

      __builtin_amdgcn_s_setprio(1);
#pragma unroll
      for (int ni = 0; ni < 4; ++ni)
#pragma unroll
        for (int mi = 0; mi < 8; ++mi)
          acc[mi][ni] = __builtin_amdgcn_mfma_f32_16x16x32_bf16(af[mi], bfr[ni], acc[mi][ni], 0, 0, 0);
      __builtin_amdgcn_s_setprio(0);

      asm volatile("s_waitcnt vmcnt(6)" ::: "memory");
      __builtin_amdgcn_s_barrier();
      __builtin_amdgcn_sched_barrier(0);
#pragma unroll
      for (int ni = 0; ni < 4; ++ni)
        bfr[ni] = __builtin_bit_cast(bf16x8, LBn[bbase + ni * 128 + ck]);
#pragma unroll
      for (int mi = 0; mi < 8; ++mi)
        af[mi] = __builtin_bit_cast(bf16x8, LAn[abase + mi * 128 + ck]);

      cur = nxt;
    }

    asm volatile("s_waitcnt vmcnt(0) lgkmcnt(0)" ::: "memory");
    __builtin_amdgcn_s_barrier();

    // pair half-exchange via LDS scratch
    f32x4* scr = (f32x4*)lds;
    {
      f32x4* mw = scr + wave * 1024;
      if (kh == 0) {
#pragma unroll
        for (int mi = 0; mi < 8; ++mi)
#pragma unroll
          for (int nl = 0; nl < 2; ++nl)
            mw[(mi * 2 + nl) * 64 + lane] = acc[mi][2 + nl];
      } else {
#pragma unroll
        for (int mi = 0; mi < 8; ++mi)
#pragma unroll
          for (int nl = 0; nl < 2; ++nl)
            mw[(mi * 2 + nl) * 64 + lane] = acc[mi][nl];
      }
    }
    __syncthreads();
    {
      const f32x4* pw = scr + (wave ^ 1) * 1024;
      if (kh == 0) {
#pragma unroll
        for (int mi = 0; mi < 8; ++mi)
#pragma unroll
          for (int nl = 0; nl < 2; ++nl)
            acc[mi][nl] += pw[(mi * 2 + nl) * 64 + lane];
      } else {
#pragma unroll
        for (int mi = 0; mi < 8; ++mi)
#pragma unroll
          for (int nl = 0; nl < 2; ++nl)
            acc[mi][2 + nl] += pw[(mi * 2 + nl) * 64 + lane];
      }
    }

    const float* Ap = A + (size_t)g * S_N + bm + wm * 128;
    const float* Cp = C + (size_t)g * X_N + bn + wn * 64 + kh * 32;
    float cv[2];
    cv[0] = Cp[r]; cv[1] = Cp[16 + r];
#pragma unroll
    for (int mi = 0; mi < 8; ++mi) {
#pragma unroll
      for (int i = 0; i < 4; ++i) {
        int rowl = mi * 16 + q * 4 + i;
        float av = Ap[rowl];
        float* orow = logits + ((size_t)g * S_N + bm + wm * 128 + rowl) * X_N + bn + wn * 64 + kh * 32;
        if (kh == 0) {
          orow[r]      = acc[mi][0][i] - 0.5f * (av + cv[0]);
          orow[16 + r] = acc[mi][1][i] - 0.5f * (av + cv[1]);
        } else {
          orow[r]      = acc[mi][2][i] - 0.5f * (av + cv[0]);
          orow[16 + r] = acc[mi][3][i] - 0.5f * (av + cv[1]);
        }
      }
    }
  }
  gridbar(sync + 1);

  // ============ phase 2: LSE, 8 waves/block, 1 row per wave =================
  {
    int wv = t >> 6, l = t & 63;
    int s = bid * 8 + wv;              // 0..2047
    const float4* p0 = (const float4*)(logits + (size_t)s * X_N);
    const float4* p1 = (const float4*)(logits + ((size_t)S_N + s) * X_N);
    float4 v[16];
#pragma unroll
    for (int k = 0; k < 8; ++k) { v[k] = p0[l + k * 64]; v[8 + k] = p1[l + k * 64]; }
    float m = v[0].x;
#pragma unroll
    for (int k = 0; k < 16; ++k) {
      m = fmaxf(m, v[k].x); m = fmaxf(m, v[k].y);
      m = fmaxf(m, v[k].z); m = fmaxf(m, v[k].w);
    }
    for (int o = 32; o; o >>= 1) m = fmaxf(m, __shfl_xor(m, o));
    float sum = 0.f;
#pragma unroll
    for (int k = 0; k < 16; ++k) {
      sum += expf(v[k].x - m) + expf(v[k].y - m) + expf(v[k].z - m) + expf(v[k].w - m);
    }
    for (int o = 32; o; o >>= 1) sum += __shfl_xor(sum, o);
    if (l == 0) out[s] = m + logf(sum) - 8.317766166719343f;  // log(4096)
  }
}

extern "C" void kernel_launch(void* const* d_in, const int* in_sizes, int n_in,
                              void* d_out, int out_size, void* d_ws, size_t ws_size,
                              hipStream_t stream) {
  const float* samples = (const float*)d_in[0];  // [S, F] fp32
  const float* xin     = (const float*)d_in[1];  // [X, F] fp32
  const float* stdv    = (const float*)d_in[2];  // [G, F] fp32
  float* out = (float*)d_out;                    // [S] fp32

  char* ws = (char*)d_ws;
  size_t off = 0;
  bf16* U = (bf16*)(ws + off);        off += (size_t)G_N * S_N * F_N * 2;  // 25.2 MB
  bf16* V = (bf16*)(ws + off);        off += (size_t)G_N * X_N * F_N * 2;  // 25.2 MB
  float* logits = (float*)(ws + off); off += (size_t)G_N * S_N * X_N * 4;  // 33.6 MB
  float* A = (float*)(ws + off);      off += (size_t)G_N * S_N * 4;
  float* C = (float*)(ws + off);      off += (size_t)G_N * X_N * 4;
  unsigned int* sync = (unsigned int*)(ws + off); off += 256;

  // zero the grid-barrier counters every launch (graph-capturable)
  hipMemsetAsync(sync, 0, 8, stream);
  k_mega<<<dim3(256), dim3(512), 0, stream>>>(samples, xin, stdv, U, V, A, C,
                                              logits, out, sync);
}

// Round 11
// 152.180 us; speedup vs baseline: 1.5953x; 1.5953x over previous
//
#include <hip/hip_runtime.h>
#include <math.h>
#include <stdint.h>

#define S_N 2048
#define X_N 2048
#define G_N 2
#define F_N 3072

// GEMM tile: 256(M) x 128(N), BK=64, 512 threads = 8 waves.
// 4 wave-positions of 128x64 output; 2 waves per position split the K-tile
// (kh = wave&1 takes k-chunks 0..3 / 4..7), pair-summed via LDS scratch.
#define TM 256
#define TN 128
#define BK 64
#define ITERS (F_N / BK)  // 48
#define NBUF 3            // triple buffer: no vmcnt(0) drain in main loop

typedef __bf16 bf16;
typedef __bf16 bf16x4 __attribute__((ext_vector_type(4)));
typedef __bf16 bf16x8 __attribute__((ext_vector_type(8)));
typedef float f32x4 __attribute__((ext_vector_type(4)));
typedef int i32x4 __attribute__((ext_vector_type(4)));

__device__ __forceinline__ void gload_lds16(const bf16* g, void* l) {
  __builtin_amdgcn_global_load_lds(
      (const __attribute__((address_space(1))) void*)g,
      (__attribute__((address_space(3))) void*)l, 16, 0, 0);
}

// ---------------- P0: prep, asymmetric factorization -------------------------
// u·v_g = sum_f s_f * (x_f * w_gf): U = bf16(s) is g-INDEPENDENT (12.6 MB,
// written once, A-panels shared by 32 gemm blocks), V_g = bf16(x*w_g).
// Matching norms keep the quadratic consistent in the rounded operands:
//   A'[g,s] = sum s~^2 w_g - 2*constg[g]   (s~ = bf16(s))
//   C[g,x]  = sum (y^*std_g)^2             (y^ = bf16(x*w_g), y^*std = y^/sqrt(w))
// => logits = -0.5*(A'+C) + u.v = -0.5 sum w (s~ - y^/w)^2 + const: exact
// quadratic, error = one bf16 rounding per operand (same class as before).
__global__ __launch_bounds__(512) void k_prep(
    const float* __restrict__ samples, const float* __restrict__ xin,
    const float* __restrict__ stdv,
    bf16* __restrict__ U, bf16* __restrict__ V,
    float* __restrict__ A, float* __restrict__ C) {
  __shared__ float rlds[12288];  // [0,6144): rinv g0|g1; [6144,12288): std g0|g1
  __shared__ float redp[16];
  int t = threadIdx.x;
  int bid = blockIdx.x;
  int lane = t & 63, wv = t >> 6;

  for (int i = t; i < 2 * F_N; i += 512) {
    float v = stdv[i];
    rlds[6144 + i] = v;
    rlds[i] = 1.0f / v;
  }

  // constg per block (redundant, cheap): sum log(std) per g
  float sl0 = 0.f, sl1 = 0.f;
  for (int i = t; i < F_N; i += 512) {
    sl0 += logf(stdv[i]);
    sl1 += logf(stdv[F_N + i]);
  }
  for (int o = 32; o; o >>= 1) { sl0 += __shfl_xor(sl0, o); sl1 += __shfl_xor(sl1, o); }
  if (lane == 0) { redp[wv] = sl0; redp[8 + wv] = sl1; }
  __syncthreads();  // also publishes rlds
  float t0 = 0.f, t1 = 0.f;
#pragma unroll
  for (int w2 = 0; w2 < 8; ++w2) { t0 += redp[w2]; t1 += redp[8 + w2]; }
  const float KLOG = -0.5f * (float)F_N * 1.8378770664093453f;
  float c0 = KLOG - t0, c1 = KLOG - t1;

  // 16 rows per block, 32 lanes per row, 24 float4 chunks per lane.
  // Blocks 0..127 are sample rows, 128..255 are x rows (uniform per block).
  int l32 = t & 31;
  int rr = bid * 16 + (t >> 5);        // 0..4095
  bool isS = rr < S_N;
  int rx = isS ? rr : rr - S_N;
  const float* src = isS ? samples + (size_t)rx * F_N : xin + (size_t)rx * F_N;

  if (isS) {
    bf16* d = U + (size_t)rx * F_N;
    float a0 = 0.f, a1 = 0.f;
#pragma unroll 4
    for (int k = 0; k < 24; ++k) {
      int c4 = l32 + k * 32;
      float4 sv = ((const float4*)src)[c4];
      float4 r0 = ((const float4*)rlds)[c4];
      float4 r1 = ((const float4*)rlds)[768 + c4];
      bf16x4 b;
      b[0] = (bf16)sv.x; b[1] = (bf16)sv.y; b[2] = (bf16)sv.z; b[3] = (bf16)sv.w;
      ((bf16x4*)d)[c4] = b;
      float f0 = (float)b[0], f1 = (float)b[1], f2 = (float)b[2], f3 = (float)b[3];
      a0 += f0 * f0 * (r0.x * r0.x) + f1 * f1 * (r0.y * r0.y)
          + f2 * f2 * (r0.z * r0.z) + f3 * f3 * (r0.w * r0.w);
      a1 += f0 * f0 * (r1.x * r1.x) + f1 * f1 * (r1.y * r1.y)
          + f2 * f2 * (r1.z * r1.z) + f3 * f3 * (r1.w * r1.w);
    }
    for (int o = 16; o; o >>= 1) { a0 += __shfl_xor(a0, o); a1 += __shfl_xor(a1, o); }
    if (l32 == 0) { A[rx] = a0 - 2.f * c0; A[S_N + rx] = a1 - 2.f * c1; }
  } else {
    bf16* d0 = V + (size_t)rx * F_N;
    bf16* d1 = V + ((size_t)X_N + rx) * F_N;
    const float* slds = rlds + 6144;
    float q0 = 0.f, q1 = 0.f;
#pragma unroll 4
    for (int k = 0; k < 24; ++k) {
      int c4 = l32 + k * 32;
      float4 xv = ((const float4*)src)[c4];
      float4 r0 = ((const float4*)rlds)[c4];
      float4 r1 = ((const float4*)rlds)[768 + c4];
      float4 s0 = ((const float4*)slds)[c4];
      float4 s1 = ((const float4*)slds)[768 + c4];
      bf16x4 y0, y1;
      y0[0] = (bf16)(xv.x * r0.x * r0.x); y0[1] = (bf16)(xv.y * r0.y * r0.y);
      y0[2] = (bf16)(xv.z * r0.z * r0.z); y0[3] = (bf16)(xv.w * r0.w * r0.w);
      y1[0] = (bf16)(xv.x * r1.x * r1.x); y1[1] = (bf16)(xv.y * r1.y * r1.y);
      y1[2] = (bf16)(xv.z * r1.z * r1.z); y1[3] = (bf16)(xv.w * r1.w * r1.w);
      ((bf16x4*)d0)[c4] = y0;
      ((bf16x4*)d1)[c4] = y1;
      float g0 = (float)y0[0] * s0.x, g1 = (float)y0[1] * s0.y;
      float g2 = (float)y0[2] * s0.z, g3 = (float)y0[3] * s0.w;
      q0 += g0 * g0 + g1 * g1 + g2 * g2 + g3 * g3;
      float h0 = (float)y1[0] * s1.x, h1 = (float)y1[1] * s1.y;
      float h2 = (float)y1[2] * s1.z, h3 = (float)y1[3] * s1.w;
      q1 += h0 * h0 + h1 * h1 + h2 * h2 + h3 * h3;
    }
    for (int o = 16; o; o >>= 1) { q0 += __shfl_xor(q0, o); q1 += __shfl_xor(q1, o); }
    if (l32 == 0) { C[rx] = q0; C[X_N + rx] = q1; }
  }
}

// ---------------- P1: logits[g,s,x] = (u v_g^T)[s,x] - 0.5*(A'[g,s]+C[g,x]) -
// R8 core verbatim (best measured 54.2us): single barrier + counted vmcnt(6)
// per K-tile, consumption-ordered reads, ni-outer MFMA nest, setprio, flat
// 3-D grid (R9 showed XCD swizzle costs ~3us in this L3-fit regime).
// Only change: U is g-independent (Ub drops the g term).
__global__ __launch_bounds__(512, 2) void k_gemm(const bf16* __restrict__ U, const bf16* __restrict__ V,
                                                 const float* __restrict__ A, const float* __restrict__ C,
                                                 float* __restrict__ logits) {
  __shared__ i32x4 lds[NBUF * 2048 + NBUF * 1024];  // 144 KiB
  i32x4* ldsA = lds;
  i32x4* ldsB = lds + NBUF * 2048;

  int t = threadIdx.x;
  int g = blockIdx.z;
  int bm = blockIdx.y * TM;
  int bn = blockIdx.x * TN;

  const bf16* Ub = U + (size_t)bm * F_N;                      // g-independent
  const bf16* Vb = V + ((size_t)g * X_N + bn) * F_N;

  int wave = t >> 6, lane = t & 63;
  int pos = wave >> 1;
  int kh = wave & 1;
  int wm = pos >> 1;
  int wn = pos & 1;
  int r = lane & 15, q = lane >> 4;
  int fr = (r >> 1) & 7;
  int ck = (kh * 4 + q) ^ fr;
  int abase = (wm * 128 + r) * 8;
  int bbase = (wn * 64 + r) * 8;

  int row0 = t >> 3;
  int gcc = (t & 7) ^ ((t >> 4) & 7);
  const bf16* gA[4];
  const bf16* gB[2];
#pragma unroll
  for (int j = 0; j < 4; ++j) gA[j] = Ub + (size_t)(row0 + j * 64) * F_N + gcc * 8;
#pragma unroll
  for (int j = 0; j < 2; ++j) gB[j] = Vb + (size_t)(row0 + j * 64) * F_N + gcc * 8;

  f32x4 acc[8][4] = {};
  bf16x8 af[8], bfr[4];

#pragma unroll
  for (int j = 0; j < 4; ++j) gload_lds16(gA[j], &ldsA[0 * 2048 + t + j * 512]);
#pragma unroll
  for (int j = 0; j < 2; ++j) gload_lds16(gB[j], &ldsB[0 * 1024 + t + j * 512]);
#pragma unroll
  for (int j = 0; j < 4; ++j) gload_lds16(gA[j] + BK, &ldsA[1 * 2048 + t + j * 512]);
#pragma unroll
  for (int j = 0; j < 2; ++j) gload_lds16(gB[j] + BK, &ldsB[1 * 1024 + t + j * 512]);
  asm volatile("s_waitcnt vmcnt(6)" ::: "memory");
  __builtin_amdgcn_s_barrier();
  __builtin_amdgcn_sched_barrier(0);
#pragma unroll
  for (int ni = 0; ni < 4; ++ni)
    bfr[ni] = __builtin_bit_cast(bf16x8, ldsB[bbase + ni * 128 + ck]);
#pragma unroll
  for (int mi = 0; mi < 8; ++mi)
    af[mi] = __builtin_bit_cast(bf16x8, ldsA[abase + mi * 128 + ck]);

  int cur = 0;
  for (int it = 0; it < ITERS; ++it) {
    int k2 = it + 2;
    int pk = (k2 < ITERS ? k2 : 0) * BK;
    int stg = (cur >= 1) ? cur - 1 : 2;
    int nxt = (cur == 2) ? 0 : cur + 1;
    const i32x4* LAn = ldsA + nxt * 2048;
    const i32x4* LBn = ldsB + nxt * 1024;

    gload_lds16(gA[0] + pk, &ldsA[stg * 2048 + t]);
    gload_lds16(gA[1] + pk, &ldsA[stg * 2048 + t + 512]);
    gload_lds16(gA[2] + pk, &ldsA[stg * 2048 + t + 1024]);
    gload_lds16(gA[3] + pk, &ldsA[stg * 2048 + t + 1536]);
    gload_lds16(gB[0] + pk, &ldsB[stg * 1024 + t]);
    gload_lds16(gB[1] + pk, &ldsB[stg * 1024 + t + 512]);

    __builtin_amdgcn_s_setprio(1);
#pragma unroll
    for (int ni = 0; ni < 4; ++ni)
#pragma unroll
      for (int mi = 0; mi < 8; ++mi)
        acc[mi][ni] = __builtin_amdgcn_mfma_f32_16x16x32_bf16(af[mi], bfr[ni], acc[mi][ni], 0, 0, 0);
    __builtin_amdgcn_s_setprio(0);

    asm volatile("s_waitcnt vmcnt(6)" ::: "memory");
    __builtin_amdgcn_s_barrier();
    __builtin_amdgcn_sched_barrier(0);
#pragma unroll
    for (int ni = 0; ni < 4; ++ni)
      bfr[ni] = __builtin_bit_cast(bf16x8, LBn[bbase + ni * 128 + ck]);
#pragma unroll
    for (int mi = 0; mi < 8; ++mi)
      af[mi] = __builtin_bit_cast(bf16x8, LAn[abase + mi * 128 + ck]);

    cur = nxt;
  }

  asm volatile("s_waitcnt vmcnt(0) lgkmcnt(0)" ::: "memory");
  __builtin_amdgcn_s_barrier();

  // pair half-exchange: wave w and w^1 share one 128x64 output.
  f32x4* scr = (f32x4*)lds;
  {
    f32x4* mw = scr + wave * 1024;
    if (kh == 0) {
#pragma unroll
      for (int mi = 0; mi < 8; ++mi)
#pragma unroll
        for (int nl = 0; nl < 2; ++nl)
          mw[(mi * 2 + nl) * 64 + lane] = acc[mi][2 + nl];
    } else {
#pragma unroll
      for (int mi = 0; mi < 8; ++mi)
#pragma unroll
        for (int nl = 0; nl < 2; ++nl)
          mw[(mi * 2 + nl) * 64 + lane] = acc[mi][nl];
    }
  }
  __syncthreads();
  {
    const f32x4* pw = scr + (wave ^ 1) * 1024;
    if (kh == 0) {
#pragma unroll
      for (int mi = 0; mi < 8; ++mi)
#pragma unroll
        for (int nl = 0; nl < 2; ++nl)
          acc[mi][nl] += pw[(mi * 2 + nl) * 64 + lane];
    } else {
#pragma unroll
      for (int mi = 0; mi < 8; ++mi)
#pragma unroll
        for (int nl = 0; nl < 2; ++nl)
          acc[mi][2 + nl] += pw[(mi * 2 + nl) * 64 + lane];
    }
  }

  const float* Ap = A + (size_t)g * S_N + bm + wm * 128;
  const float* Cp = C + (size_t)g * X_N + bn + wn * 64 + kh * 32;
  float cv[2];
  cv[0] = Cp[r]; cv[1] = Cp[16 + r];
#pragma unroll
  for (int mi = 0; mi < 8; ++mi) {
#pragma unroll
    for (int i = 0; i < 4; ++i) {
      int rowl = mi * 16 + q * 4 + i;
      float av = Ap[rowl];
      float* orow = logits + ((size_t)g * S_N + bm + wm * 128 + rowl) * X_N + bn + wn * 64 + kh * 32;
      if (kh == 0) {
        orow[r]      = acc[mi][0][i] - 0.5f * (av + cv[0]);
        orow[16 + r] = acc[mi][1][i] - 0.5f * (av + cv[1]);
      } else {
        orow[r]      = acc[mi][2][i] - 0.5f * (av + cv[0]);
        orow[16 + r] = acc[mi][3][i] - 0.5f * (av + cv[1]);
      }
    }
  }
}

// ---------------- P2: out[s] = LSE over (g,x) of logits - log(X*G) ----------
__global__ void k_lse(const float* __restrict__ logits, float* __restrict__ out) {
  int s = blockIdx.x, t = threadIdx.x;
  const float4* p0 = (const float4*)(logits + (size_t)s * X_N);
  const float4* p1 = (const float4*)(logits + ((size_t)S_N + s) * X_N);
  float4 v[4];
  v[0] = p0[t]; v[1] = p0[t + 256];
  v[2] = p1[t]; v[3] = p1[t + 256];

  float m = v[0].x;
#pragma unroll
  for (int j = 0; j < 4; ++j) {
    m = fmaxf(m, v[j].x); m = fmaxf(m, v[j].y);
    m = fmaxf(m, v[j].z); m = fmaxf(m, v[j].w);
  }
  for (int o = 32; o; o >>= 1) m = fmaxf(m, __shfl_xor(m, o));
  __shared__ float redm[4];
  __shared__ float reds[4];
  int w = t >> 6, l = t & 63;
  if (l == 0) redm[w] = m;
  __syncthreads();
  m = fmaxf(fmaxf(redm[0], redm[1]), fmaxf(redm[2], redm[3]));

  float sum = 0.f;
#pragma unroll
  for (int j = 0; j < 4; ++j) {
    sum += expf(v[j].x - m) + expf(v[j].y - m) + expf(v[j].z - m) + expf(v[j].w - m);
  }
  for (int o = 32; o; o >>= 1) sum += __shfl_xor(sum, o);
  if (l == 0) reds[w] = sum;
  __syncthreads();
  if (t == 0) {
    float tot = reds[0] + reds[1] + reds[2] + reds[3];
    out[s] = m + logf(tot) - 8.317766166719343f;  // log(4096)
  }
}

extern "C" void kernel_launch(void* const* d_in, const int* in_sizes, int n_in,
                              void* d_out, int out_size, void* d_ws, size_t ws_size,
                              hipStream_t stream) {
  const float* samples = (const float*)d_in[0];  // [S, F] fp32
  const float* xin     = (const float*)d_in[1];  // [X, F] fp32
  const float* stdv    = (const float*)d_in[2];  // [G, F] fp32
  float* out = (float*)d_out;                    // [S] fp32

  char* ws = (char*)d_ws;
  size_t off = 0;
  bf16* U = (bf16*)(ws + off);        off += (size_t)S_N * F_N * 2;          // 12.6 MB (g-independent)
  bf16* V = (bf16*)(ws + off);        off += (size_t)G_N * X_N * F_N * 2;    // 25.2 MB
  float* logits = (float*)(ws + off); off += (size_t)G_N * S_N * X_N * 4;    // 33.6 MB
  float* A = (float*)(ws + off);      off += (size_t)G_N * S_N * 4;
  float* C = (float*)(ws + off);      off += (size_t)G_N * X_N * 4;

  k_prep<<<dim3(256), dim3(512), 0, stream>>>(samples, xin, stdv, U, V, A, C);
  k_gemm<<<dim3(X_N / TN, S_N / TM, G_N), dim3(512), 0, stream>>>(U, V, A, C, logits);
  k_lse<<<dim3(S_N), dim3(256), 0, stream>>>(logits, out);
}